// Round 5
// baseline (112.289 us; speedup 1.0000x reference)
//
#include <hip/hip_runtime.h>

// Dense image warp (bilinear, tfa interpolate_bilinear semantics)
// x:    [B, H, W, C] fp32   (B=4, H=512, W=512, C=64)
// flow: [B, H, W, 2] fp32
// out:  [B, H, W, C] fp32
//
// R5: persistent-row kernel. 2048 blocks x 256 threads; each block owns ONE
// image row (512 px), looping 16 iterations x 32 px. vs R4 (one-shot blocks):
//  - loop iterations are independent -> compiler software-pipelines next
//    iteration's gathers under current iteration's stores (deep MLP/wave)
//  - h, b, row/batch base pointers are loop-invariant (less per-pixel VALU)
//  - 16x fewer blocks -> less launch/drain tail
// Keeps: XCD slab swizzle (XCD k owns 256 contiguous rows), nt flow load,
// nt out store, 8 lanes/px x 2 float4 chunks.

typedef float f32x4 __attribute__((ext_vector_type(4)));
typedef float f32x2 __attribute__((ext_vector_type(2)));

constexpr int BD = 4;
constexpr int HD = 512;
constexpr int WD = 512;
constexpr int CD = 64;
constexpr int NROWS   = BD * HD;              // 2048 = grid size
constexpr int NXCD    = 8;
constexpr int RPX     = NROWS / NXCD;         // 256 rows per XCD
constexpr int ITERS   = WD / 32;              // 16 (32 px per iteration)

__global__ __launch_bounds__(256) void warp_bilinear_kernel(
    const float* __restrict__ x,
    const float* __restrict__ flow,
    float* __restrict__ out)
{
    // XCD swizzle: default dispatch round-robins blockIdx.x across the 8
    // XCDs; remap so XCD k executes rows [k*256, (k+1)*256) — a contiguous
    // half-image slab whose 2-row x reuse window lives in one private L2.
    const int row = (blockIdx.x & (NXCD - 1)) * RPX + (blockIdx.x >> 3);

    const int h = row & (HD - 1);
    const int b = row >> 9;                   // row / H
    const int pg  = threadIdx.x >> 3;         // pixel-in-group [0,32)
    const int sub = threadIdx.x & 7;
    const int c0  = sub << 2;                 // channels c0..c0+3, c0+32..+35

    const float* xb = x + (size_t)b * HD * WD * CD + c0;   // batch+channel base
    const size_t rowpix = (size_t)row * WD;                // flat pixel base
    const float hf = (float)h;

#pragma unroll 4
    for (int i = 0; i < ITERS; ++i) {
        const int w = i * 32 + pg;
        const size_t p = rowpix + w;

        const f32x2 fl =
            __builtin_nontemporal_load(reinterpret_cast<const f32x2*>(flow) + p);
        const float qx = (float)w + fl.x;
        const float qy = hf + fl.y;

        // tfa: floor clamped to [0, size-2], alpha clamped to [0, 1]
        const float fxf = fminf(fmaxf(floorf(qx), 0.0f), (float)(WD - 2));
        const float fyf = fminf(fmaxf(floorf(qy), 0.0f), (float)(HD - 2));
        const float ax = fminf(fmaxf(qx - fxf, 0.0f), 1.0f);
        const float ay = fminf(fmaxf(qy - fyf, 0.0f), 1.0f);
        const int fx = (int)fxf;
        const int fy = (int)fyf;

        const float* basep = xb + ((size_t)fy * WD + fx) * CD;
        const float* baseb = basep + (size_t)WD * CD;      // row fy+1

        const f32x4 tl0 = *reinterpret_cast<const f32x4*>(basep);
        const f32x4 tl1 = *reinterpret_cast<const f32x4*>(basep + 32);
        const f32x4 tr0 = *reinterpret_cast<const f32x4*>(basep + CD);
        const f32x4 tr1 = *reinterpret_cast<const f32x4*>(basep + CD + 32);
        const f32x4 bl0 = *reinterpret_cast<const f32x4*>(baseb);
        const f32x4 bl1 = *reinterpret_cast<const f32x4*>(baseb + 32);
        const f32x4 br0 = *reinterpret_cast<const f32x4*>(baseb + CD);
        const f32x4 br1 = *reinterpret_cast<const f32x4*>(baseb + CD + 32);

        f32x4 it0 = (tr0 - tl0) * ax + tl0;
        f32x4 ib0 = (br0 - bl0) * ax + bl0;
        f32x4 o0  = (ib0 - it0) * ay + it0;

        f32x4 it1 = (tr1 - tl1) * ax + tl1;
        f32x4 ib1 = (br1 - bl1) * ax + bl1;
        f32x4 o1  = (ib1 - it1) * ay + it1;

        f32x4* op = reinterpret_cast<f32x4*>(out + p * CD + c0);
        __builtin_nontemporal_store(o0, op);
        __builtin_nontemporal_store(o1, op + 8);           // +32 floats
    }
}

extern "C" void kernel_launch(void* const* d_in, const int* in_sizes, int n_in,
                              void* d_out, int out_size, void* d_ws, size_t ws_size,
                              hipStream_t stream) {
    const float* x    = (const float*)d_in[0];
    const float* flow = (const float*)d_in[1];
    float* out        = (float*)d_out;

    warp_bilinear_kernel<<<NROWS, 256, 0, stream>>>(x, flow, out);
}

// Round 6
// 100.624 us; speedup vs baseline: 1.1159x; 1.1159x over previous
//
#include <hip/hip_runtime.h>

// Dense image warp (bilinear, tfa interpolate_bilinear semantics)
// x:    [B, H, W, C] fp32   (B=4, H=512, W=512, C=64)
// flow: [B, H, W, 2] fp32
// out:  [B, H, W, C] fp32
//
// R6: R4's one-shot many-block structure + TWO pixels per thread.
//  - 16384 blocks x 256 threads; block owns 64 consecutive pixels of one row;
//    thread (pg,sub) handles pixels pg and pg+32, channels [c0,c0+4) and
//    [c0+32,c0+36) of each.
//  - Both flow loads issue together; all 16 corner gathers in flight at once
//    -> exposed gather latency per pixel halves vs R4.
//  - int32 index math (x has 2^26 elements, offsets fit) shortens addr chain.
//  - R5 lesson: many short blocks >> few long blocks (no imbalance/drain).
// Keeps: XCD slab swizzle, nt flow loads, nt out stores.

typedef float f32x4 __attribute__((ext_vector_type(4)));
typedef float f32x2 __attribute__((ext_vector_type(2)));

constexpr int BD = 4;
constexpr int HD = 512;
constexpr int WD = 512;
constexpr int CD = 64;
constexpr int PXB = 64;                        // pixels per block
constexpr int NBLOCKS = BD * HD * WD / PXB;    // 16384
constexpr int NXCD = 8;
constexpr int CHUNK = NBLOCKS / NXCD;          // 2048 (exact)

__global__ __launch_bounds__(256) void warp_bilinear_kernel(
    const float* __restrict__ x,
    const float* __restrict__ flow,
    float* __restrict__ out)
{
    // XCD swizzle: each XCD owns a contiguous slab of the image.
    const int bid = (blockIdx.x & (NXCD - 1)) * CHUNK + (blockIdx.x >> 3);

    const int pbase = bid * PXB;
    const int pg  = threadIdx.x >> 3;          // pixel-in-block [0,32)
    const int sub = threadIdx.x & 7;
    const int c0  = sub << 2;                  // channels c0..c0+3, c0+32..+35

    const int p0 = pbase + pg;                 // both pixels in the same row
    const int p1 = p0 + 32;

    // row decode (shared by p0,p1: 64-px block never crosses a row)
    const int row = p0 >> 9;                   // p / W
    const int h   = row & (HD - 1);
    const int b   = row >> 9;                  // row / H
    const float hf = (float)h;
    const int w0  = p0 & (WD - 1);
    const int xb  = b * (HD * WD * CD) + c0;   // batch+channel base (int ok: 2^26)

    // two independent flow loads
    const f32x2 fl0 =
        __builtin_nontemporal_load(reinterpret_cast<const f32x2*>(flow) + p0);
    const f32x2 fl1 =
        __builtin_nontemporal_load(reinterpret_cast<const f32x2*>(flow) + p1);

    // tfa: floor clamped to [0, size-2], alpha clamped to [0, 1]
    float ax0, ay0, ax1, ay1;
    int i0, i1;
    {
        const float qx = (float)w0 + fl0.x;
        const float qy = hf + fl0.y;
        const float fxf = fminf(fmaxf(floorf(qx), 0.0f), (float)(WD - 2));
        const float fyf = fminf(fmaxf(floorf(qy), 0.0f), (float)(HD - 2));
        ax0 = fminf(fmaxf(qx - fxf, 0.0f), 1.0f);
        ay0 = fminf(fmaxf(qy - fyf, 0.0f), 1.0f);
        i0 = xb + ((int)fyf * WD + (int)fxf) * CD;
    }
    {
        const float qx = (float)(w0 + 32) + fl1.x;
        const float qy = hf + fl1.y;
        const float fxf = fminf(fmaxf(floorf(qx), 0.0f), (float)(WD - 2));
        const float fyf = fminf(fmaxf(floorf(qy), 0.0f), (float)(HD - 2));
        ax1 = fminf(fmaxf(qx - fxf, 0.0f), 1.0f);
        ay1 = fminf(fmaxf(qy - fyf, 0.0f), 1.0f);
        i1 = xb + ((int)fyf * WD + (int)fxf) * CD;
    }

    const float* t0 = x + i0;                  // pixel0 top row
    const float* b0 = t0 + WD * CD;            // pixel0 bottom row
    const float* t1 = x + i1;
    const float* b1 = t1 + WD * CD;

    // 16 independent gathers, all in flight
    const f32x4 tl0a = *reinterpret_cast<const f32x4*>(t0);
    const f32x4 tl0b = *reinterpret_cast<const f32x4*>(t0 + 32);
    const f32x4 tr0a = *reinterpret_cast<const f32x4*>(t0 + CD);
    const f32x4 tr0b = *reinterpret_cast<const f32x4*>(t0 + CD + 32);
    const f32x4 bl0a = *reinterpret_cast<const f32x4*>(b0);
    const f32x4 bl0b = *reinterpret_cast<const f32x4*>(b0 + 32);
    const f32x4 br0a = *reinterpret_cast<const f32x4*>(b0 + CD);
    const f32x4 br0b = *reinterpret_cast<const f32x4*>(b0 + CD + 32);
    const f32x4 tl1a = *reinterpret_cast<const f32x4*>(t1);
    const f32x4 tl1b = *reinterpret_cast<const f32x4*>(t1 + 32);
    const f32x4 tr1a = *reinterpret_cast<const f32x4*>(t1 + CD);
    const f32x4 tr1b = *reinterpret_cast<const f32x4*>(t1 + CD + 32);
    const f32x4 bl1a = *reinterpret_cast<const f32x4*>(b1);
    const f32x4 bl1b = *reinterpret_cast<const f32x4*>(b1 + 32);
    const f32x4 br1a = *reinterpret_cast<const f32x4*>(b1 + CD);
    const f32x4 br1b = *reinterpret_cast<const f32x4*>(b1 + CD + 32);

    f32x4 it, ib, o0a, o0b, o1a, o1b;
    it = (tr0a - tl0a) * ax0 + tl0a;
    ib = (br0a - bl0a) * ax0 + bl0a;
    o0a = (ib - it) * ay0 + it;
    it = (tr0b - tl0b) * ax0 + tl0b;
    ib = (br0b - bl0b) * ax0 + bl0b;
    o0b = (ib - it) * ay0 + it;
    it = (tr1a - tl1a) * ax1 + tl1a;
    ib = (br1a - bl1a) * ax1 + bl1a;
    o1a = (ib - it) * ay1 + it;
    it = (tr1b - tl1b) * ax1 + tl1b;
    ib = (br1b - bl1b) * ax1 + bl1b;
    o1b = (ib - it) * ay1 + it;

    f32x4* op0 = reinterpret_cast<f32x4*>(out + p0 * CD + c0);
    f32x4* op1 = reinterpret_cast<f32x4*>(out + p1 * CD + c0);
    __builtin_nontemporal_store(o0a, op0);
    __builtin_nontemporal_store(o0b, op0 + 8);
    __builtin_nontemporal_store(o1a, op1);
    __builtin_nontemporal_store(o1b, op1 + 8);
}

extern "C" void kernel_launch(void* const* d_in, const int* in_sizes, int n_in,
                              void* d_out, int out_size, void* d_ws, size_t ws_size,
                              hipStream_t stream) {
    const float* x    = (const float*)d_in[0];
    const float* flow = (const float*)d_in[1];
    float* out        = (float*)d_out;

    warp_bilinear_kernel<<<NBLOCKS, 256, 0, stream>>>(x, flow, out);
}